// Round 4
// baseline (2056.585 us; speedup 1.0000x reference)
//
#include <hip/hip_runtime.h>
#include <math.h>

#define B_ 64
#define S_ 2048
#define H_ 1024
#define K_ 1024
#define M_ (B_*S_)   // 131072 rows of the big GEMM

using f32x4   = __attribute__((ext_vector_type(4))) float;
using bf16x8  = __attribute__((ext_vector_type(8))) __bf16;

#define SB() __builtin_amdgcn_sched_barrier(0)

__device__ __forceinline__ unsigned short f2b(float f) {
  unsigned int u = __float_as_uint(f);
  u += 0x7fffu + ((u >> 16) & 1u);   // RNE
  return (unsigned short)(u >> 16);
}

// tanh(x) = (e^2x - 1)/(e^2x + 1); clamp so t stays finite (tanh saturated anyway)
__device__ __forceinline__ float fast_tanh(float x) {
  float xc = fminf(fmaxf(x, -15.f), 15.f);
  float t = __expf(2.f * xc);
  return (t - 1.f) * __builtin_amdgcn_rcpf(t + 1.f);
}

typedef __attribute__((address_space(1))) void gvoid_t;
typedef __attribute__((address_space(3))) void lvoid_t;

__device__ __forceinline__ void async16(const void* g, void* l) {
  __builtin_amdgcn_global_load_lds((gvoid_t*)g, (lvoid_t*)l, 16, 0, 0);
}

// XOR-swizzled LDS element offset for (row r, 16B-slot sl) in a [128][32] bf16 tile
__device__ __forceinline__ int swz(int r, int sl) {
  return r * 32 + ((sl ^ ((r >> 1) & 3)) << 3);
}

// ---------------------------------------------------------------- mask dtype
// flag: 0 = int32 {0,1}, 1 = bytes (bool), 2 = float32 {0,1.0}
__global__ void detect_mask(const unsigned int* __restrict__ m, int* __restrict__ flag) {
  __shared__ int red[256];
  int t = threadIdx.x;
  int f = 0;
  for (int i = 0; i < 32; ++i) {
    unsigned int w = m[t * 32 + i];
    if (w > 1u) f |= 1;
    if (w != 0u && w != 0x3f800000u) f |= 2;
  }
  red[t] = f;
  __syncthreads();
  for (int o = 128; o > 0; o >>= 1) { if (t < o) red[t] |= red[t + o]; __syncthreads(); }
  if (t == 0) {
    int g = red[0];
    *flag = ((g & 1) == 0) ? 0 : (((g & 2) == 0) ? 2 : 1);
  }
}

// ---------------------------------------------------------------- Wk -> bf16
__global__ void convert_wk(const float* __restrict__ src, unsigned short* __restrict__ dst) {
  int i = blockIdx.x * blockDim.x + threadIdx.x;
  float4 v = ((const float4*)src)[i];
  ushort4 o;
  o.x = f2b(v.x); o.y = f2b(v.y); o.z = f2b(v.z); o.w = f2b(v.w);
  *(ushort4*)(dst + (size_t)i * 4) = o;
}

// ---------------------------------------------------------------- qp = query @ Wq.T
__global__ void qp_kernel(const float* __restrict__ query, const float* __restrict__ Wq,
                          float* __restrict__ qp) {
  __shared__ float qs[1024];
  const int b = blockIdx.x, t = threadIdx.x;
  ((float4*)qs)[t] = ((const float4*)(query + b * 1024))[t];
  __syncthreads();
#pragma unroll
  for (int i = 0; i < 4; ++i) {
    int h = t + i * 256;
    const float4* wr = (const float4*)(Wq + h * 1024);
    float s = 0.f;
    for (int q4 = 0; q4 < 256; ++q4) {
      float4 w = wr[q4];
      float4 q = ((const float4*)qs)[q4];
      s += w.x * q.x + w.y * q.y + w.z * q.z + w.w * q.w;
    }
    qp[b * 1024 + h] = s;
  }
}

// ---------------------------------------------------------------- fused GEMM + energy
// Pipelined m97-variant: raw s_barrier + COUNTED vmcnt (never drain).
//   As: double-buffered, reg-staged (f32 load -> cvt bf16 -> swizzled ds_write),
//       A-prefetch loads get a 2-iteration latency window (~1000 cyc > HBM 900).
//   Bs: TRIPLE-buffered, staged 2 K-steps ahead via global_load_lds, so the
//       end-of-iter wait for B[kt+1] (vmcnt(10)) never retires the younger
//       A-prefetch (FIFO issue order: [P@kt-1, B@kt-1, Bstage@kt, P@kt]).
// One barrier per K-step; sched_barrier(0) pins each issue group.
__global__ __launch_bounds__(256) void gemm_energy(
    const float* __restrict__ keys,          // [M_][1024] f32
    const __bf16* __restrict__ wk,           // [1024][1024] bf16 (B^T layout)
    const float* __restrict__ qp,            // [64][1024]
    const float* __restrict__ v,             // [1024]
    float* __restrict__ energy) {            // [M_]
  __shared__ __align__(16) __bf16 As[2][128 * 32];
  __shared__ __align__(16) __bf16 Bs[3][128 * 32];

  const int tid  = threadIdx.x;
  const int w    = tid >> 6;
  const int lane = tid & 63;

  // XCD-bijective swizzle: all 8 n-tiles of one m-tile consecutive on one XCD
  const int orig = blockIdx.x;                   // 0..8191
  const int wgid = (orig & 7) * 1024 + (orig >> 3);
  const int m0 = (wgid >> 3) * 128;
  const int n0 = (wgid & 7) * 128;

  const int wm = w >> 1, wn = w & 1;

  f32x4 acc[4][4] = {};

  // A staging: this thread owns 2 chunks of 8 f32 per K-step
  int arow[2], aslot[2];
#pragma unroll
  for (int i = 0; i < 2; ++i) {
    int c = tid + i * 256;
    arow[i]  = c >> 2;
    aslot[i] = c & 3;
  }
  const float* Abase = keys + (size_t)m0 * K_;

  // B stage source (pre-swizzled global column so linear LDS dest = swizzled layout)
  int brow[2], bs_src[2], bs_dst[2];
#pragma unroll
  for (int j = 0; j < 2; ++j) {
    int flat = w * 1024 + j * 512 + lane * 8;
    brow[j]   = flat >> 5;
    bs_src[j] = (((flat >> 3) & 3) ^ ((brow[j] >> 1) & 3)) * 8;
    bs_dst[j] = w * 1024 + j * 512;
  }

  // ---- prologue ----
  float4 a0[2][2];                 // direct loads for kt=0
#pragma unroll
  for (int i = 0; i < 2; ++i) {
    const float* p = Abase + arow[i] * K_ + aslot[i] * 8;
    a0[i][0] = *(const float4*)p;
    a0[i][1] = *(const float4*)(p + 4);
  }
  SB();
#pragma unroll
  for (int j = 0; j < 2; ++j)   // stage Bs[0] (k-tile 0)
    async16(wk + (size_t)(n0 + brow[j]) * K_ + 0 + bs_src[j], &Bs[0][bs_dst[j]]);
#pragma unroll
  for (int j = 0; j < 2; ++j)   // stage Bs[1] (k-tile 1)
    async16(wk + (size_t)(n0 + brow[j]) * K_ + 32 + bs_src[j], &Bs[1][bs_dst[j]]);
  SB();
  float4 P[2][2][2];               // P[buf][chunk][half] ; P[0]=rows k-tile1, P[1]=k-tile2
#pragma unroll
  for (int b = 0; b < 2; ++b)
#pragma unroll
    for (int i = 0; i < 2; ++i) {
      const float* p = Abase + arow[i] * K_ + (b + 1) * 32 + aslot[i] * 8;
      P[b][i][0] = *(const float4*)p;
      P[b][i][1] = *(const float4*)(p + 4);
    }
  SB();
#pragma unroll
  for (int i = 0; i < 2; ++i) {    // cvt + write As[0]
    bf16x8 u;
    u[0] = (__bf16)a0[i][0].x; u[1] = (__bf16)a0[i][0].y;
    u[2] = (__bf16)a0[i][0].z; u[3] = (__bf16)a0[i][0].w;
    u[4] = (__bf16)a0[i][1].x; u[5] = (__bf16)a0[i][1].y;
    u[6] = (__bf16)a0[i][1].z; u[7] = (__bf16)a0[i][1].w;
    *(bf16x8*)(&As[0][swz(arow[i], aslot[i])]) = u;
  }
  asm volatile("s_waitcnt vmcnt(10)" ::: "memory");  // Bs[0] slices done (keep B1,P0,P1)
  asm volatile("s_waitcnt lgkmcnt(0)" ::: "memory");
  SB(); __builtin_amdgcn_s_barrier(); SB();

  // ---- main loop: one barrier per K-step, counted vmcnt ----
  for (int kt = 0; kt < 32; ++kt) {
    const int curA = kt & 1, nxtA = curA ^ 1;
    const int curB = kt % 3;
    const int stgB = (kt + 2) % 3;
    const int kStg = (kt + 2 < 32 ? kt + 2 : 31) * 32;   // clamped (tail writes unused)
    const int kPre = (kt + 3 < 32 ? kt + 3 : 31) * 32;

    // s1: cvt P[curA] (rows k-tile kt+1) -> As[nxtA]  (compiler auto-waits P regs)
#pragma unroll
    for (int i = 0; i < 2; ++i) {
      bf16x8 u;
      u[0] = (__bf16)P[curA][i][0].x; u[1] = (__bf16)P[curA][i][0].y;
      u[2] = (__bf16)P[curA][i][0].z; u[3] = (__bf16)P[curA][i][0].w;
      u[4] = (__bf16)P[curA][i][1].x; u[5] = (__bf16)P[curA][i][1].y;
      u[6] = (__bf16)P[curA][i][1].z; u[7] = (__bf16)P[curA][i][1].w;
      *(bf16x8*)(&As[nxtA][swz(arow[i], aslot[i])]) = u;
    }
    SB();
    // s2: stage Bs for k-tile kt+2
#pragma unroll
    for (int j = 0; j < 2; ++j)
      async16(wk + (size_t)(n0 + brow[j]) * K_ + kStg + bs_src[j], &Bs[stgB][bs_dst[j]]);
    SB();
    // s3: reload P[curA] <- rows of k-tile kt+3 (consumed at kt+2)
#pragma unroll
    for (int i = 0; i < 2; ++i) {
      const float* p = Abase + arow[i] * K_ + kPre + aslot[i] * 8;
      P[curA][i][0] = *(const float4*)p;
      P[curA][i][1] = *(const float4*)(p + 4);
    }
    SB();
    // s4: fragments + MFMA
    const int g = lane >> 4;
    bf16x8 af[4], bf[4];
#pragma unroll
    for (int mi = 0; mi < 4; ++mi) {
      int r = wm * 64 + mi * 16 + (lane & 15);
      af[mi] = *(const bf16x8*)(&As[curA][swz(r, g)]);
    }
#pragma unroll
    for (int ni = 0; ni < 4; ++ni) {
      int r = wn * 64 + ni * 16 + (lane & 15);
      bf[ni] = *(const bf16x8*)(&Bs[curB][swz(r, g)]);
    }
#pragma unroll
    for (int mi = 0; mi < 4; ++mi)
#pragma unroll
      for (int ni = 0; ni < 4; ++ni)
        acc[mi][ni] = __builtin_amdgcn_mfma_f32_16x16x32_bf16(af[mi], bf[ni], acc[mi][ni], 0, 0, 0);
    // end: wait MY B[kt+1] slices (10 newer ops stay in flight: P@kt-1(4), Bstage@kt(2), P@kt(4))
    asm volatile("s_waitcnt vmcnt(10)" ::: "memory");
    asm volatile("s_waitcnt lgkmcnt(0)" ::: "memory");
    SB(); __builtin_amdgcn_s_barrier(); SB();
  }

  // epilogue: C/D layout col = lane&15, row = (lane>>4)*4 + reg
  const int bb = m0 >> 11;
  float qpv[4], vv[4];
#pragma unroll
  for (int ni = 0; ni < 4; ++ni) {
    int h = n0 + wn * 64 + ni * 16 + (lane & 15);
    qpv[ni] = qp[bb * H_ + h];
    vv[ni]  = v[h];
  }
#pragma unroll
  for (int mi = 0; mi < 4; ++mi) {
    float ps[4] = {0.f, 0.f, 0.f, 0.f};
#pragma unroll
    for (int ni = 0; ni < 4; ++ni)
#pragma unroll
      for (int rr = 0; rr < 4; ++rr)
        ps[rr] += fast_tanh(acc[mi][ni][rr] + qpv[ni]) * vv[ni];
#pragma unroll
    for (int off = 1; off < 16; off <<= 1)
#pragma unroll
      for (int rr = 0; rr < 4; ++rr)
        ps[rr] += __shfl_xor(ps[rr], off, 64);
    if ((lane & 15) == 0) {
      int rowbase = m0 + wm * 64 + mi * 16 + (lane >> 4) * 4;
#pragma unroll
      for (int rr = 0; rr < 4; ++rr)
        atomicAdd(&energy[rowbase + rr], ps[rr]);
    }
  }
}

// ---------------------------------------------------------------- masked softmax
__global__ void softmax_kernel(const float* __restrict__ energy, const void* __restrict__ mask,
                               const int* __restrict__ flag, float* __restrict__ attn) {
  __shared__ float red[256];
  const int b = blockIdx.x, t = threadIdx.x;
  const int fl = *flag;
  float e[8];
#pragma unroll
  for (int i = 0; i < 8; ++i) {
    int s = i * 256 + t;
    int idx = b * S_ + s;
    bool m;
    if (fl == 1)      m = ((const unsigned char*)mask)[idx] != 0;
    else if (fl == 2) m = ((const float*)mask)[idx] != 0.f;
    else              m = ((const int*)mask)[idx] != 0;
    e[i] = m ? -INFINITY : energy[idx];
  }
  float mx = e[0];
#pragma unroll
  for (int i = 1; i < 8; ++i) mx = fmaxf(mx, e[i]);
  red[t] = mx; __syncthreads();
  for (int o = 128; o > 0; o >>= 1) { if (t < o) red[t] = fmaxf(red[t], red[t + o]); __syncthreads(); }
  mx = red[0];
  __syncthreads();
  const bool any = (mx > -INFINITY);
  float p[8]; float sum = 0.f;
#pragma unroll
  for (int i = 0; i < 8; ++i) {
    p[i] = (any && e[i] > -INFINITY) ? __expf(e[i] - mx) : 0.f;
    sum += p[i];
  }
  red[t] = sum; __syncthreads();
  for (int o = 128; o > 0; o >>= 1) { if (t < o) red[t] += red[t + o]; __syncthreads(); }
  sum = red[0];
  const float inv = (sum > 0.f) ? 1.f / sum : 0.f;
#pragma unroll
  for (int i = 0; i < 8; ++i) attn[b * S_ + i * 256 + t] = p[i] * inv;
}

// ---------------------------------------------------------------- context = attn @ keys
__global__ void context_kernel(const float* __restrict__ attn, const float* __restrict__ keys,
                               float* __restrict__ ctx) {
  const int b = blockIdx.y;
  const int sc = blockIdx.x;          // 16 chunks of 128 s
  const int t = threadIdx.x;          // k = 4t..4t+3
  const float* kb = keys + ((size_t)b * S_ + sc * 128) * K_;
  const float* ab = attn + b * S_ + sc * 128;
  float4 acc = {0.f, 0.f, 0.f, 0.f};
  for (int s = 0; s < 128; ++s) {
    float a = ab[s];                   // block-uniform
    if (a != 0.f) {                    // skip padded positions entirely
      float4 kv = *(const float4*)(kb + (size_t)s * K_ + t * 4);
      acc.x += a * kv.x; acc.y += a * kv.y; acc.z += a * kv.z; acc.w += a * kv.w;
    }
  }
  float* cb = ctx + b * K_ + t * 4;
  atomicAdd(cb + 0, acc.x);
  atomicAdd(cb + 1, acc.y);
  atomicAdd(cb + 2, acc.z);
  atomicAdd(cb + 3, acc.w);
}

// ---------------------------------------------------------------- launch
extern "C" void kernel_launch(void* const* d_in, const int* in_sizes, int n_in,
                              void* d_out, int out_size, void* d_ws, size_t ws_size,
                              hipStream_t stream) {
  (void)in_sizes; (void)n_in; (void)out_size; (void)ws_size;
  const float* query = (const float*)d_in[0];
  const float* keys  = (const float*)d_in[1];
  const void*  mask  = d_in[2];
  const float* Wq    = (const float*)d_in[3];
  const float* Wk    = (const float*)d_in[4];
  const float* v     = (const float*)d_in[5];

  float* ctx  = (float*)d_out;             // [64][1024]
  float* attn = (float*)d_out + B_ * K_;   // [64][2048]

  char* ws = (char*)d_ws;
  float*          energy = (float*)ws;                              // 512 KiB
  float*          qp     = (float*)(ws + (512 << 10));              // 256 KiB
  unsigned short* wkb    = (unsigned short*)(ws + (768 << 10));     // 2 MiB
  int*            flag   = (int*)(ws + (768 << 10) + (2 << 20));

  hipMemsetAsync(energy, 0, (size_t)M_ * 4, stream);
  hipMemsetAsync(ctx, 0, (size_t)B_ * K_ * 4, stream);
  detect_mask<<<1, 256, 0, stream>>>((const unsigned int*)mask, flag);
  convert_wk<<<(H_ * K_ / 4) / 256, 256, 0, stream>>>(Wk, wkb);
  qp_kernel<<<B_, 256, 0, stream>>>(query, Wq, qp);
  gemm_energy<<<(M_ / 128) * (H_ / 128), 256, 0, stream>>>(keys, (const __bf16*)wkb, qp, v, energy);
  softmax_kernel<<<B_, 256, 0, stream>>>(energy, mask, flag, attn);
  context_kernel<<<dim3(S_ / 128, B_), 256, 0, stream>>>(attn, keys, ctx);
}

// Round 5
// 886.974 us; speedup vs baseline: 2.3187x; 2.3187x over previous
//
#include <hip/hip_runtime.h>
#include <math.h>

#define B_ 64
#define S_ 2048
#define H_ 1024
#define K_ 1024
#define M_ (B_*S_)   // 131072 rows of the big GEMM

using f32x4   = __attribute__((ext_vector_type(4))) float;
using bf16x8  = __attribute__((ext_vector_type(8))) __bf16;

#define SB() __builtin_amdgcn_sched_barrier(0)

__device__ __forceinline__ unsigned short f2b(float f) {
  unsigned int u = __float_as_uint(f);
  u += 0x7fffu + ((u >> 16) & 1u);   // RNE
  return (unsigned short)(u >> 16);
}

// tanh(x) = (e^2x - 1)/(e^2x + 1); clamp so t stays finite (tanh saturated anyway)
__device__ __forceinline__ float fast_tanh(float x) {
  float xc = fminf(fmaxf(x, -15.f), 15.f);
  float t = __expf(2.f * xc);
  return (t - 1.f) * __builtin_amdgcn_rcpf(t + 1.f);
}

typedef __attribute__((address_space(1))) void gvoid_t;
typedef __attribute__((address_space(3))) void lvoid_t;

__device__ __forceinline__ void async16(const void* g, void* l) {
  __builtin_amdgcn_global_load_lds((gvoid_t*)g, (lvoid_t*)l, 16, 0, 0);
}

// XOR-swizzled LDS element offset for (row r, 16B-slot sl) in a [128][32] bf16 tile
__device__ __forceinline__ int swz(int r, int sl) {
  return r * 32 + ((sl ^ ((r >> 1) & 3)) << 3);
}

// ---------------------------------------------------------------- mask dtype
// flag: 0 = int32 {0,1}, 1 = bytes (bool), 2 = float32 {0,1.0}
__global__ void detect_mask(const unsigned int* __restrict__ m, int* __restrict__ flag) {
  __shared__ int red[256];
  int t = threadIdx.x;
  int f = 0;
  for (int i = 0; i < 32; ++i) {
    unsigned int w = m[t * 32 + i];
    if (w > 1u) f |= 1;
    if (w != 0u && w != 0x3f800000u) f |= 2;
  }
  red[t] = f;
  __syncthreads();
  for (int o = 128; o > 0; o >>= 1) { if (t < o) red[t] |= red[t + o]; __syncthreads(); }
  if (t == 0) {
    int g = red[0];
    *flag = ((g & 1) == 0) ? 0 : (((g & 2) == 0) ? 2 : 1);
  }
}

// ---------------------------------------------------------------- Wk -> bf16
__global__ void convert_wk(const float* __restrict__ src, unsigned short* __restrict__ dst) {
  int i = blockIdx.x * blockDim.x + threadIdx.x;
  float4 v = ((const float4*)src)[i];
  ushort4 o;
  o.x = f2b(v.x); o.y = f2b(v.y); o.z = f2b(v.z); o.w = f2b(v.w);
  *(ushort4*)(dst + (size_t)i * 4) = o;
}

// ---------------------------------------------------------------- qp = query @ Wq.T
__global__ void qp_kernel(const float* __restrict__ query, const float* __restrict__ Wq,
                          float* __restrict__ qp) {
  __shared__ float qs[1024];
  const int b = blockIdx.x, t = threadIdx.x;
  ((float4*)qs)[t] = ((const float4*)(query + b * 1024))[t];
  __syncthreads();
#pragma unroll
  for (int i = 0; i < 4; ++i) {
    int h = t + i * 256;
    const float4* wr = (const float4*)(Wq + h * 1024);
    float s = 0.f;
    for (int q4 = 0; q4 < 256; ++q4) {
      float4 w = wr[q4];
      float4 q = ((const float4*)qs)[q4];
      s += w.x * q.x + w.y * q.y + w.z * q.z + w.w * q.w;
    }
    qp[b * 1024 + h] = s;
  }
}

// ---------------------------------------------------------------- fused GEMM + energy
// Pipelined: raw s_barrier + COUNTED vmcnt (never drain). Same sync structure
// as R4 (correctness-proven) but the A-prefetch register buffers are NAMED
// (P0/P1, loop unrolled x2) so all register indexing is compile-time static —
// no scratch (rule #20). Bs[curB] runtime index is LDS addressing: fine.
__global__ __launch_bounds__(256) void gemm_energy(
    const float* __restrict__ keys,          // [M_][1024] f32
    const __bf16* __restrict__ wk,           // [1024][1024] bf16 (B^T layout)
    const float* __restrict__ qp,            // [64][1024]
    const float* __restrict__ v,             // [1024]
    float* __restrict__ energy) {            // [M_]
  __shared__ __align__(16) __bf16 As[2][128 * 32];
  __shared__ __align__(16) __bf16 Bs[3][128 * 32];

  const int tid  = threadIdx.x;
  const int w    = tid >> 6;
  const int lane = tid & 63;

  // XCD-bijective swizzle: all 8 n-tiles of one m-tile consecutive on one XCD
  const int orig = blockIdx.x;                   // 0..8191
  const int wgid = (orig & 7) * 1024 + (orig >> 3);
  const int m0 = (wgid >> 3) * 128;
  const int n0 = (wgid & 7) * 128;

  const int wm = w >> 1, wn = w & 1;

  f32x4 acc[4][4] = {};

  // A staging: this thread owns 2 chunks of 8 f32 per K-step
  int arow[2], aslot[2];
#pragma unroll
  for (int i = 0; i < 2; ++i) {
    int c = tid + i * 256;
    arow[i]  = c >> 2;
    aslot[i] = c & 3;
  }
  const float* Abase = keys + (size_t)m0 * K_;

  // B stage source (pre-swizzled global column so linear LDS dest = swizzled layout)
  int brow[2], bs_src[2], bs_dst[2];
#pragma unroll
  for (int j = 0; j < 2; ++j) {
    int flat = w * 1024 + j * 512 + lane * 8;
    brow[j]   = flat >> 5;
    bs_src[j] = (((flat >> 3) & 3) ^ ((brow[j] >> 1) & 3)) * 8;
    bs_dst[j] = w * 1024 + j * 512;
  }

  // ---- prologue ----
  float4 a00, a01, a10, a11;       // direct loads for kt=0 (static names)
  {
    const float* p0 = Abase + arow[0] * K_ + aslot[0] * 8;
    const float* p1 = Abase + arow[1] * K_ + aslot[1] * 8;
    a00 = *(const float4*)p0; a01 = *(const float4*)(p0 + 4);
    a10 = *(const float4*)p1; a11 = *(const float4*)(p1 + 4);
  }
  SB();
#pragma unroll
  for (int j = 0; j < 2; ++j)   // stage Bs[0] (k-tile 0)
    async16(wk + (size_t)(n0 + brow[j]) * K_ + 0 + bs_src[j], &Bs[0][bs_dst[j]]);
#pragma unroll
  for (int j = 0; j < 2; ++j)   // stage Bs[1] (k-tile 1)
    async16(wk + (size_t)(n0 + brow[j]) * K_ + 32 + bs_src[j], &Bs[1][bs_dst[j]]);
  SB();
  float4 P0[2][2], P1[2][2];       // P0 = rows of k-tile 1, P1 = rows of k-tile 2
#pragma unroll
  for (int i = 0; i < 2; ++i) {
    const float* p = Abase + arow[i] * K_ + 32 + aslot[i] * 8;
    P0[i][0] = *(const float4*)p;
    P0[i][1] = *(const float4*)(p + 4);
  }
#pragma unroll
  for (int i = 0; i < 2; ++i) {
    const float* p = Abase + arow[i] * K_ + 64 + aslot[i] * 8;
    P1[i][0] = *(const float4*)p;
    P1[i][1] = *(const float4*)(p + 4);
  }
  SB();
  {                                 // cvt + write As[0] (k-tile 0)
    bf16x8 u;
    u[0] = (__bf16)a00.x; u[1] = (__bf16)a00.y;
    u[2] = (__bf16)a00.z; u[3] = (__bf16)a00.w;
    u[4] = (__bf16)a01.x; u[5] = (__bf16)a01.y;
    u[6] = (__bf16)a01.z; u[7] = (__bf16)a01.w;
    *(bf16x8*)(&As[0][swz(arow[0], aslot[0])]) = u;
    bf16x8 u2;
    u2[0] = (__bf16)a10.x; u2[1] = (__bf16)a10.y;
    u2[2] = (__bf16)a10.z; u2[3] = (__bf16)a10.w;
    u2[4] = (__bf16)a11.x; u2[5] = (__bf16)a11.y;
    u2[6] = (__bf16)a11.z; u2[7] = (__bf16)a11.w;
    *(bf16x8*)(&As[1][0]) = u2;  // placeholder slot? NO — see below
  }
  // (the second chunk write above must go to As[0] as well — fixed here)
  // NOTE: corrected in GSTEP-equivalent below; see real write:
  {
    // re-write chunk 1 to its proper As[0] location (the As[1][0] write above
    // is harmless garbage that gets overwritten before As[1] is consumed)
    bf16x8 u2;
    u2[0] = (__bf16)a10.x; u2[1] = (__bf16)a10.y;
    u2[2] = (__bf16)a10.z; u2[3] = (__bf16)a10.w;
    u2[4] = (__bf16)a11.x; u2[5] = (__bf16)a11.y;
    u2[6] = (__bf16)a11.z; u2[7] = (__bf16)a11.w;
    *(bf16x8*)(&As[0][swz(arow[1], aslot[1])]) = u2;
  }
  asm volatile("s_waitcnt vmcnt(10)" ::: "memory");  // Bs[0] done (keep B1,P0,P1)
  asm volatile("s_waitcnt lgkmcnt(0)" ::: "memory");
  SB(); __builtin_amdgcn_s_barrier(); SB();

  // ---- main loop: unrolled x2, all register indices static ----
#define GSTEP(KT, CUR, NXT, PV, CURB)                                          \
  {                                                                            \
    const int kStg = ((KT) + 2 < 32 ? (KT) + 2 : 31) * 32;                     \
    const int kPre = ((KT) + 3 < 32 ? (KT) + 3 : 31) * 32;                     \
    const int stgB = ((CURB) + 2 >= 3) ? (CURB) - 1 : (CURB) + 2;              \
    _Pragma("unroll")                                                          \
    for (int i = 0; i < 2; ++i) {                                              \
      bf16x8 u;                                                                \
      u[0] = (__bf16)PV[i][0].x; u[1] = (__bf16)PV[i][0].y;                    \
      u[2] = (__bf16)PV[i][0].z; u[3] = (__bf16)PV[i][0].w;                    \
      u[4] = (__bf16)PV[i][1].x; u[5] = (__bf16)PV[i][1].y;                    \
      u[6] = (__bf16)PV[i][1].z; u[7] = (__bf16)PV[i][1].w;                    \
      *(bf16x8*)(&As[NXT][swz(arow[i], aslot[i])]) = u;                        \
    }                                                                          \
    SB();                                                                      \
    _Pragma("unroll")                                                          \
    for (int j = 0; j < 2; ++j)                                                \
      async16(wk + (size_t)(n0 + brow[j]) * K_ + kStg + bs_src[j],             \
              &Bs[stgB][bs_dst[j]]);                                           \
    SB();                                                                      \
    _Pragma("unroll")                                                          \
    for (int i = 0; i < 2; ++i) {                                              \
      const float* p = Abase + arow[i] * K_ + kPre + aslot[i] * 8;             \
      PV[i][0] = *(const float4*)p;                                            \
      PV[i][1] = *(const float4*)(p + 4);                                      \
    }                                                                          \
    SB();                                                                      \
    {                                                                          \
      const int g = lane >> 4;                                                 \
      bf16x8 af[4], bfr[4];                                                    \
      _Pragma("unroll")                                                        \
      for (int mi = 0; mi < 4; ++mi) {                                         \
        int r = wm * 64 + mi * 16 + (lane & 15);                               \
        af[mi] = *(const bf16x8*)(&As[CUR][swz(r, g)]);                        \
      }                                                                        \
      _Pragma("unroll")                                                        \
      for (int ni = 0; ni < 4; ++ni) {                                         \
        int r = wn * 64 + ni * 16 + (lane & 15);                               \
        bfr[ni] = *(const bf16x8*)(&Bs[CURB][swz(r, g)]);                      \
      }                                                                        \
      _Pragma("unroll")                                                        \
      for (int mi = 0; mi < 4; ++mi)                                           \
        _Pragma("unroll")                                                      \
        for (int ni = 0; ni < 4; ++ni)                                         \
          acc[mi][ni] = __builtin_amdgcn_mfma_f32_16x16x32_bf16(               \
              af[mi], bfr[ni], acc[mi][ni], 0, 0, 0);                          \
    }                                                                          \
    asm volatile("s_waitcnt vmcnt(10)" ::: "memory");                          \
    asm volatile("s_waitcnt lgkmcnt(0)" ::: "memory");                         \
    SB(); __builtin_amdgcn_s_barrier(); SB();                                  \
  }

  int curB = 0;
  for (int kt = 0; kt < 32; kt += 2) {
    GSTEP(kt, 0, 1, P0, curB);
    curB = (curB == 2) ? 0 : curB + 1;
    GSTEP(kt + 1, 1, 0, P1, curB);
    curB = (curB == 2) ? 0 : curB + 1;
  }
#undef GSTEP

  // epilogue: C/D layout col = lane&15, row = (lane>>4)*4 + reg
  const int bb = m0 >> 11;
  float qpv[4], vv[4];
#pragma unroll
  for (int ni = 0; ni < 4; ++ni) {
    int h = n0 + wn * 64 + ni * 16 + (lane & 15);
    qpv[ni] = qp[bb * H_ + h];
    vv[ni]  = v[h];
  }
#pragma unroll
  for (int mi = 0; mi < 4; ++mi) {
    float ps[4] = {0.f, 0.f, 0.f, 0.f};
#pragma unroll
    for (int ni = 0; ni < 4; ++ni)
#pragma unroll
      for (int rr = 0; rr < 4; ++rr)
        ps[rr] += fast_tanh(acc[mi][ni][rr] + qpv[ni]) * vv[ni];
#pragma unroll
    for (int off = 1; off < 16; off <<= 1)
#pragma unroll
      for (int rr = 0; rr < 4; ++rr)
        ps[rr] += __shfl_xor(ps[rr], off, 64);
    if ((lane & 15) == 0) {
      int rowbase = m0 + wm * 64 + mi * 16 + (lane >> 4) * 4;
#pragma unroll
      for (int rr = 0; rr < 4; ++rr)
        atomicAdd(&energy[rowbase + rr], ps[rr]);
    }
  }
}

// ---------------------------------------------------------------- masked softmax
__global__ void softmax_kernel(const float* __restrict__ energy, const void* __restrict__ mask,
                               const int* __restrict__ flag, float* __restrict__ attn) {
  __shared__ float red[256];
  const int b = blockIdx.x, t = threadIdx.x;
  const int fl = *flag;
  float e[8];
#pragma unroll
  for (int i = 0; i < 8; ++i) {
    int s = i * 256 + t;
    int idx = b * S_ + s;
    bool m;
    if (fl == 1)      m = ((const unsigned char*)mask)[idx] != 0;
    else if (fl == 2) m = ((const float*)mask)[idx] != 0.f;
    else              m = ((const int*)mask)[idx] != 0;
    e[i] = m ? -INFINITY : energy[idx];
  }
  float mx = e[0];
#pragma unroll
  for (int i = 1; i < 8; ++i) mx = fmaxf(mx, e[i]);
  red[t] = mx; __syncthreads();
  for (int o = 128; o > 0; o >>= 1) { if (t < o) red[t] = fmaxf(red[t], red[t + o]); __syncthreads(); }
  mx = red[0];
  __syncthreads();
  const bool any = (mx > -INFINITY);
  float p[8]; float sum = 0.f;
#pragma unroll
  for (int i = 0; i < 8; ++i) {
    p[i] = (any && e[i] > -INFINITY) ? __expf(e[i] - mx) : 0.f;
    sum += p[i];
  }
  red[t] = sum; __syncthreads();
  for (int o = 128; o > 0; o >>= 1) { if (t < o) red[t] += red[t + o]; __syncthreads(); }
  sum = red[0];
  const float inv = (sum > 0.f) ? 1.f / sum : 0.f;
#pragma unroll
  for (int i = 0; i < 8; ++i) attn[b * S_ + i * 256 + t] = p[i] * inv;
}

// ---------------------------------------------------------------- context = attn @ keys
__global__ void context_kernel(const float* __restrict__ attn, const float* __restrict__ keys,
                               float* __restrict__ ctx) {
  const int b = blockIdx.y;
  const int sc = blockIdx.x;          // 16 chunks of 128 s
  const int t = threadIdx.x;          // k = 4t..4t+3
  const float* kb = keys + ((size_t)b * S_ + sc * 128) * K_;
  const float* ab = attn + b * S_ + sc * 128;
  float4 acc = {0.f, 0.f, 0.f, 0.f};
  for (int s = 0; s < 128; ++s) {
    float a = ab[s];                   // block-uniform
    if (a != 0.f) {                    // skip padded positions entirely
      float4 kv = *(const float4*)(kb + (size_t)s * K_ + t * 4);
      acc.x += a * kv.x; acc.y += a * kv.y; acc.z += a * kv.z; acc.w += a * kv.w;
    }
  }
  float* cb = ctx + b * K_ + t * 4;
  atomicAdd(cb + 0, acc.x);
  atomicAdd(cb + 1, acc.y);
  atomicAdd(cb + 2, acc.z);
  atomicAdd(cb + 3, acc.w);
}

// ---------------------------------------------------------------- launch
extern "C" void kernel_launch(void* const* d_in, const int* in_sizes, int n_in,
                              void* d_out, int out_size, void* d_ws, size_t ws_size,
                              hipStream_t stream) {
  (void)in_sizes; (void)n_in; (void)out_size; (void)ws_size;
  const float* query = (const float*)d_in[0];
  const float* keys  = (const float*)d_in[1];
  const void*  mask  = d_in[2];
  const float* Wq    = (const float*)d_in[3];
  const float* Wk    = (const float*)d_in[4];
  const float* v     = (const float*)d_in[5];

  float* ctx  = (float*)d_out;             // [64][1024]
  float* attn = (float*)d_out + B_ * K_;   // [64][2048]

  char* ws = (char*)d_ws;
  float*          energy = (float*)ws;                              // 512 KiB
  float*          qp     = (float*)(ws + (512 << 10));              // 256 KiB
  unsigned short* wkb    = (unsigned short*)(ws + (768 << 10));     // 2 MiB
  int*            flag   = (int*)(ws + (768 << 10) + (2 << 20));

  hipMemsetAsync(energy, 0, (size_t)M_ * 4, stream);
  hipMemsetAsync(ctx, 0, (size_t)B_ * K_ * 4, stream);
  detect_mask<<<1, 256, 0, stream>>>((const unsigned int*)mask, flag);
  convert_wk<<<(H_ * K_ / 4) / 256, 256, 0, stream>>>(Wk, wkb);
  qp_kernel<<<B_, 256, 0, stream>>>(query, Wq, qp);
  gemm_energy<<<(M_ / 128) * (H_ / 128), 256, 0, stream>>>(keys, (const __bf16*)wkb, qp, v, energy);
  softmax_kernel<<<B_, 256, 0, stream>>>(energy, mask, flag, attn);
  context_kernel<<<dim3(S_ / 128, B_), 256, 0, stream>>>(attn, keys, ctx);
}